// Round 1
// baseline (2546.409 us; speedup 1.0000x reference)
//
#include <hip/hip_runtime.h>

#define NN 100000
#define NE 3200000
#define NG 256
#define NF (NN * 64)
#define FEPS 1e-5f

static inline int ceil_div(int a, int b) { return (a + b - 1) / b; }

__global__ __launch_bounds__(256) void k_deg_init(float* __restrict__ deg) {
    int i = blockIdx.x * 256 + threadIdx.x;
    if (i < NN) deg[i] = 1.0f;   // self-loop
}

__global__ __launch_bounds__(256) void k_deg_acc(const int* __restrict__ dst,
                                                 float* __restrict__ deg) {
    int e = blockIdx.x * 256 + threadIdx.x;
    if (e < NE) atomicAdd(&deg[dst[e]], 1.0f);
}

__global__ __launch_bounds__(256) void k_dinv(float* __restrict__ deg) {
    int i = blockIdx.x * 256 + threadIdx.x;
    if (i < NN) deg[i] = rsqrtf(deg[i]);   // deg >= 1 always (self-loop)
}

__global__ __launch_bounds__(256) void k_norm(const int* __restrict__ src,
                                              const int* __restrict__ dst,
                                              const float* __restrict__ dinv,
                                              float* __restrict__ nrm) {
    int e = blockIdx.x * 256 + threadIdx.x;
    if (e < NE) nrm[e] = dinv[src[e]] * dinv[dst[e]];
}

// T[i,f] = sum_k x[i,k] * W[k,f], Fin = 8. One wave per node, lane = f.
__global__ __launch_bounds__(256) void k_xform8(const float* __restrict__ x,
                                                const float* __restrict__ W,
                                                float* __restrict__ t) {
    __shared__ float Ws[512];
    int tid = threadIdx.x;
    for (int i = tid; i < 512; i += 256) Ws[i] = W[i];
    __syncthreads();
    int wave = (blockIdx.x * 256 + tid) >> 6;
    int lane = tid & 63;
    if (wave >= NN) return;
    float xv = x[wave * 8 + (lane & 7)];
    float acc = 0.f;
#pragma unroll
    for (int k = 0; k < 8; ++k)
        acc = fmaf(__shfl(xv, k, 64), Ws[k * 64 + lane], acc);
    t[wave * 64 + lane] = acc;
}

// T[i,f] = sum_k h[i,k] * W[k,f], Fin = 64. One wave per node, lane = f.
__global__ __launch_bounds__(256) void k_xform64(const float* __restrict__ x,
                                                 const float* __restrict__ W,
                                                 float* __restrict__ t) {
    __shared__ float Ws[4096];
    int tid = threadIdx.x;
    for (int i = tid; i < 4096; i += 256) Ws[i] = W[i];
    __syncthreads();
    int wave = (blockIdx.x * 256 + tid) >> 6;
    int lane = tid & 63;
    if (wave >= NN) return;
    float xv = x[wave * 64 + lane];
    float acc = 0.f;
#pragma unroll
    for (int k = 0; k < 64; ++k)
        acc = fmaf(__shfl(xv, k, 64), Ws[k * 64 + lane], acc);
    t[wave * 64 + lane] = acc;
}

// ACC[i,f] = T[i,f] * dinv[i]^2   (self-loop contribution; also zero-inits ACC)
__global__ __launch_bounds__(256) void k_self(const float* __restrict__ t,
                                              const float* __restrict__ dinv,
                                              float* __restrict__ acc) {
    int idx = blockIdx.x * 256 + threadIdx.x;
    if (idx >= NF) return;
    float di = dinv[idx >> 6];
    acc[idx] = t[idx] * di * di;
}

// ACC[dst,f] += T[src,f] * nrm[e]; one wave per edge (grid-stride), lane = f.
__global__ __launch_bounds__(256) void k_scatter(const int* __restrict__ src,
                                                 const int* __restrict__ dst,
                                                 const float* __restrict__ nrm,
                                                 const float* __restrict__ t,
                                                 float* __restrict__ acc) {
    int gw = (blockIdx.x * 256 + threadIdx.x) >> 6;
    int lane = threadIdx.x & 63;
    int nw = (gridDim.x * 256) >> 6;
    for (int e = gw; e < NE; e += nw) {
        int s = src[e];
        int d = dst[e];
        float v = t[s * 64 + lane] * nrm[e];
        atomicAdd(&acc[d * 64 + lane], v);
    }
}

// H[i,f] = relu(BN(ACC[i,f] + b[f]))
__global__ __launch_bounds__(256) void k_bnrelu(const float* __restrict__ acc,
                                                const float* __restrict__ b,
                                                const float* __restrict__ g,
                                                const float* __restrict__ be,
                                                const float* __restrict__ rm,
                                                const float* __restrict__ rv,
                                                float* __restrict__ h) {
    int idx = blockIdx.x * 256 + threadIdx.x;
    if (idx >= NF) return;
    int f = idx & 63;
    float v = acc[idx] + b[f];
    v = (v - rm[f]) * rsqrtf(rv[f] + FEPS) * g[f] + be[f];
    h[idx] = fmaxf(v, 0.f);
}

// Mean-pool prep: batch is SORTED, so run-length accumulate per wave, flush one
// atomic per graph boundary. CHUNK consecutive nodes per wave.
__global__ __launch_bounds__(256) void k_pool(const float* __restrict__ h,
                                              const int* __restrict__ batch,
                                              float* __restrict__ sums,
                                              float* __restrict__ cnts) {
    const int CHUNK = 32;
    int gw = (blockIdx.x * 256 + threadIdx.x) >> 6;
    int lane = threadIdx.x & 63;
    int nw = (gridDim.x * 256) >> 6;
    int nchunks = (NN + CHUNK - 1) / CHUNK;
    for (int c = gw; c < nchunks; c += nw) {
        int n0 = c * CHUNK;
        int n1 = min(n0 + CHUNK, NN);
        int gcur = batch[n0];
        float accf = 0.f;
        float cnt = 0.f;
        for (int n = n0; n < n1; ++n) {
            int gg = batch[n];
            if (gg != gcur) {
                atomicAdd(&sums[gcur * 64 + lane], accf);
                if (lane == 0) atomicAdd(&cnts[gcur], cnt);
                accf = 0.f;
                cnt = 0.f;
                gcur = gg;
            }
            accf += h[n * 64 + lane];
            cnt += 1.f;
        }
        atomicAdd(&sums[gcur * 64 + lane], accf);
        if (lane == 0) atomicAdd(&cnts[gcur], cnt);
    }
}

// out[g,:] = relu(pooled @ Wr1 + br1) @ Wr2 + br2; one wave per graph.
__global__ __launch_bounds__(256) void k_head(const float* __restrict__ sums,
                                              const float* __restrict__ cnts,
                                              const float* __restrict__ Wr1,
                                              const float* __restrict__ br1,
                                              const float* __restrict__ Wr2,
                                              const float* __restrict__ br2,
                                              float* __restrict__ out) {
    int wave = (blockIdx.x * 256 + threadIdx.x) >> 6;
    int lane = threadIdx.x & 63;
    if (wave >= NG) return;
    float c = fmaxf(cnts[wave], 1.0f);
    float pooled = sums[wave * 64 + lane] / c;
    float acc = 0.f;
#pragma unroll
    for (int k = 0; k < 64; ++k)
        acc = fmaf(__shfl(pooled, k, 64), Wr1[k * 64 + lane], acc);
    float hid = fmaxf(acc + br1[lane], 0.f);
    float o0 = hid * Wr2[lane * 2 + 0];
    float o1 = hid * Wr2[lane * 2 + 1];
#pragma unroll
    for (int off = 32; off > 0; off >>= 1) {
        o0 += __shfl_xor(o0, off, 64);
        o1 += __shfl_xor(o1, off, 64);
    }
    if (lane == 0) {
        out[wave * 2 + 0] = o0 + br2[0];
        out[wave * 2 + 1] = o1 + br2[1];
    }
}

extern "C" void kernel_launch(void* const* d_in, const int* in_sizes, int n_in,
                              void* d_out, int out_size, void* d_ws, size_t ws_size,
                              hipStream_t stream) {
    const float* x   = (const float*)d_in[0];
    const int*   ei  = (const int*)d_in[1];     // [2, E] flat: row0=src, row1=dst
    const int*   bat = (const int*)d_in[2];
    const float* W1  = (const float*)d_in[3];
    const float* b1  = (const float*)d_in[4];
    const float* g1  = (const float*)d_in[5];
    const float* be1 = (const float*)d_in[6];
    const float* rm1 = (const float*)d_in[7];
    const float* rv1 = (const float*)d_in[8];
    const float* W2  = (const float*)d_in[9];
    const float* b2  = (const float*)d_in[10];
    const float* g2  = (const float*)d_in[11];
    const float* be2 = (const float*)d_in[12];
    const float* rm2 = (const float*)d_in[13];
    const float* rv2 = (const float*)d_in[14];
    const float* W3  = (const float*)d_in[15];
    const float* b3  = (const float*)d_in[16];
    const float* g3  = (const float*)d_in[17];
    const float* be3 = (const float*)d_in[18];
    const float* rm3 = (const float*)d_in[19];
    const float* rv3 = (const float*)d_in[20];
    const float* Wr1 = (const float*)d_in[21];
    const float* br1 = (const float*)d_in[22];
    const float* Wr2 = (const float*)d_in[23];
    const float* br2 = (const float*)d_in[24];
    float* out = (float*)d_out;

    // workspace layout (floats)
    float* ws   = (float*)d_ws;
    float* dinv = ws;              // NN      (deg -> dinv in place)
    float* nrm  = dinv + NN;       // NE
    float* T    = nrm + NE;        // NF
    float* ACC  = T + NF;          // NF
    float* H    = ACC + NF;        // NF
    float* sums = H + NF;          // NG*64
    float* cnts = sums + NG * 64;  // NG

    const int* srcI = ei;
    const int* dstI = ei + NE;

    const int gN  = ceil_div(NN, 256);
    const int gE  = ceil_div(NE, 256);
    const int gF  = ceil_div(NF, 256);
    const int gSc = 12800;  // scatter grid (grid-stride)

    // degree / norm
    k_deg_init<<<gN, 256, 0, stream>>>(dinv);
    k_deg_acc<<<gE, 256, 0, stream>>>(dstI, dinv);
    k_dinv<<<gN, 256, 0, stream>>>(dinv);
    k_norm<<<gE, 256, 0, stream>>>(srcI, dstI, dinv, nrm);

    // layer 1 (8 -> 64)
    k_xform8<<<gF, 256, 0, stream>>>(x, W1, T);
    k_self<<<gF, 256, 0, stream>>>(T, dinv, ACC);
    k_scatter<<<gSc, 256, 0, stream>>>(srcI, dstI, nrm, T, ACC);
    k_bnrelu<<<gF, 256, 0, stream>>>(ACC, b1, g1, be1, rm1, rv1, H);

    // layer 2 (64 -> 64)
    k_xform64<<<gF, 256, 0, stream>>>(H, W2, T);
    k_self<<<gF, 256, 0, stream>>>(T, dinv, ACC);
    k_scatter<<<gSc, 256, 0, stream>>>(srcI, dstI, nrm, T, ACC);
    k_bnrelu<<<gF, 256, 0, stream>>>(ACC, b2, g2, be2, rm2, rv2, H);

    // layer 3 (64 -> 64)
    k_xform64<<<gF, 256, 0, stream>>>(H, W3, T);
    k_self<<<gF, 256, 0, stream>>>(T, dinv, ACC);
    k_scatter<<<gSc, 256, 0, stream>>>(srcI, dstI, nrm, T, ACC);
    k_bnrelu<<<gF, 256, 0, stream>>>(ACC, b3, g3, be3, rm3, rv3, H);

    // mean pool + head
    hipMemsetAsync(sums, 0, (NG * 64 + NG) * sizeof(float), stream);
    k_pool<<<800, 256, 0, stream>>>(H, bat, sums, cnts);
    k_head<<<ceil_div(NG * 64, 256), 256, 0, stream>>>(sums, cnts, Wr1, br1, Wr2, br2, out);
}

// Round 2
// 1011.089 us; speedup vs baseline: 2.5185x; 2.5185x over previous
//
#include <hip/hip_runtime.h>

#define NN 100000
#define NE 3200000
#define NG 256
#define NF (NN * 64)
#define FEPS 1e-5f

static inline int ceil_div(int a, int b) { return (a + b - 1) / b; }

// ---------- CSR build ----------

// cnt[dst]++ over all edges (in-degree, excluding self-loop)
__global__ __launch_bounds__(256) void k_hist(const int* __restrict__ dst,
                                              int* __restrict__ cnt) {
    int e = blockIdx.x * 256 + threadIdx.x;
    if (e < NE) atomicAdd(&cnt[dst[e]], 1);
}

// dinv[i] = rsqrt(in_deg + 1)   (+1 = self-loop)
__global__ __launch_bounds__(256) void k_dinv(const int* __restrict__ cnt,
                                              float* __restrict__ dinv) {
    int i = blockIdx.x * 256 + threadIdx.x;
    if (i < NN) dinv[i] = rsqrtf((float)cnt[i] + 1.0f);
}

// hierarchical exclusive scan of cnt[NN] -> rowptr[NN] (and cursor copy)
__global__ __launch_bounds__(256) void k_scan1(const int* __restrict__ cnt,
                                               int* __restrict__ bsum) {
    __shared__ int s[256];
    int t = threadIdx.x;
    int i = blockIdx.x * 256 + t;
    s[t] = (i < NN) ? cnt[i] : 0;
    __syncthreads();
    for (int off = 128; off > 0; off >>= 1) {
        if (t < off) s[t] += s[t + off];
        __syncthreads();
    }
    if (t == 0) bsum[blockIdx.x] = s[0];
}

__global__ __launch_bounds__(512) void k_scan2(int* __restrict__ bsum, int nb) {
    __shared__ int s[512];
    int t = threadIdx.x;
    int v = (t < nb) ? bsum[t] : 0;
    s[t] = v;
    __syncthreads();
    for (int off = 1; off < 512; off <<= 1) {
        int add = (t >= off) ? s[t - off] : 0;
        __syncthreads();
        s[t] += add;
        __syncthreads();
    }
    if (t < nb) bsum[t] = s[t] - v;   // exclusive
}

__global__ __launch_bounds__(256) void k_scan3(const int* __restrict__ cnt,
                                               const int* __restrict__ bsum,
                                               int* __restrict__ rowptr,
                                               int* __restrict__ cursor) {
    __shared__ int s[256];
    int t = threadIdx.x;
    int i = blockIdx.x * 256 + t;
    int v = (i < NN) ? cnt[i] : 0;
    s[t] = v;
    __syncthreads();
    for (int off = 1; off < 256; off <<= 1) {
        int add = (t >= off) ? s[t - off] : 0;
        __syncthreads();
        s[t] += add;
        __syncthreads();
    }
    int ex = s[t] - v + bsum[blockIdx.x];
    if (i < NN) {
        rowptr[i] = ex;
        cursor[i] = ex;
    }
}

// scatter edges into dst-grouped CSR; record = (src, norm) packed in int2
__global__ __launch_bounds__(256) void k_fill(const int* __restrict__ src,
                                              const int* __restrict__ dst,
                                              const float* __restrict__ dinv,
                                              int* __restrict__ cursor,
                                              int2* __restrict__ csr) {
    int e = blockIdx.x * 256 + threadIdx.x;
    if (e >= NE) return;
    int s = src[e];
    int d = dst[e];
    int pos = atomicAdd(&cursor[d], 1);
    csr[pos] = make_int2(s, __float_as_int(dinv[s] * dinv[d]));
}

// ---------- aggregation (gather, no atomics) ----------

// 8-wide aggregate of x: wave per node, lane = (e_sub<<3)|f; 8 edges/iter.
__global__ __launch_bounds__(256) void k_gather8(const float* __restrict__ x,
                                                 const int* __restrict__ rowptr,
                                                 const int* __restrict__ cnt,
                                                 const float* __restrict__ dinv,
                                                 const int2* __restrict__ csr,
                                                 float* __restrict__ P8) {
    int wave = (blockIdx.x * 256 + threadIdx.x) >> 6;
    int lane = threadIdx.x & 63;
    if (wave >= NN) return;
    int es = lane >> 3, f = lane & 7;
    int st = rowptr[wave], n = cnt[wave];
    float acc = 0.f;
    for (int k0 = 0; k0 < n; k0 += 8) {
        int kk = k0 + es;
        if (kk < n) {
            int2 a = csr[st + kk];
            acc = fmaf(x[a.x * 8 + f], __int_as_float(a.y), acc);
        }
    }
    acc += __shfl_xor(acc, 8, 64);
    acc += __shfl_xor(acc, 16, 64);
    acc += __shfl_xor(acc, 32, 64);
    if (lane < 8) {
        float di = dinv[wave];
        P8[wave * 8 + f] = acc + x[wave * 8 + f] * di * di;
    }
}

// 64-wide aggregate of H: wave per node, lane = f; 2-edge unroll for latency.
__global__ __launch_bounds__(256) void k_gather64(const float* __restrict__ H,
                                                  const int* __restrict__ rowptr,
                                                  const int* __restrict__ cnt,
                                                  const float* __restrict__ dinv,
                                                  const int2* __restrict__ csr,
                                                  float* __restrict__ P) {
    int wave = (blockIdx.x * 256 + threadIdx.x) >> 6;
    int lane = threadIdx.x & 63;
    if (wave >= NN) return;
    float di = dinv[wave];
    float acc = H[wave * 64 + lane] * di * di;   // self-loop
    int st = rowptr[wave], n = cnt[wave];
    int k = 0;
    for (; k + 2 <= n; k += 2) {
        int2 a = csr[st + k];
        int2 b = csr[st + k + 1];
        float va = H[a.x * 64 + lane];
        float vb = H[b.x * 64 + lane];
        acc = fmaf(va, __int_as_float(a.y), acc);
        acc = fmaf(vb, __int_as_float(b.y), acc);
    }
    if (k < n) {
        int2 a = csr[st + k];
        acc = fmaf(H[a.x * 64 + lane], __int_as_float(a.y), acc);
    }
    P[wave * 64 + lane] = acc;
}

// ---------- fused transform + bias + BN + ReLU ----------

__global__ __launch_bounds__(256) void k_xf8bn(const float* __restrict__ P8,
                                               const float* __restrict__ W,
                                               const float* __restrict__ b,
                                               const float* __restrict__ g,
                                               const float* __restrict__ be,
                                               const float* __restrict__ rm,
                                               const float* __restrict__ rv,
                                               float* __restrict__ H) {
    __shared__ float Ws[512];
    int tid = threadIdx.x;
    for (int i = tid; i < 512; i += 256) Ws[i] = W[i];
    __syncthreads();
    int wave = (blockIdx.x * 256 + tid) >> 6;
    int lane = tid & 63;
    if (wave >= NN) return;
    float scale = g[lane] * rsqrtf(rv[lane] + FEPS);
    float shift = be[lane] + (b[lane] - rm[lane]) * scale;
    float pf = P8[wave * 8 + (lane & 7)];
    float acc = 0.f;
#pragma unroll
    for (int k = 0; k < 8; ++k)
        acc = fmaf(__shfl(pf, k, 64), Ws[k * 64 + lane], acc);
    H[wave * 64 + lane] = fmaxf(fmaf(acc, scale, shift), 0.f);
}

__global__ __launch_bounds__(256) void k_xf64bn(const float* __restrict__ P,
                                                const float* __restrict__ W,
                                                const float* __restrict__ b,
                                                const float* __restrict__ g,
                                                const float* __restrict__ be,
                                                const float* __restrict__ rm,
                                                const float* __restrict__ rv,
                                                float* __restrict__ H) {
    __shared__ float Ws[4096];
    int tid = threadIdx.x;
    for (int i = tid; i < 4096; i += 256) Ws[i] = W[i];
    __syncthreads();
    int wave = (blockIdx.x * 256 + tid) >> 6;
    int lane = tid & 63;
    if (wave >= NN) return;
    float scale = g[lane] * rsqrtf(rv[lane] + FEPS);
    float shift = be[lane] + (b[lane] - rm[lane]) * scale;
    float pv = P[wave * 64 + lane];
    float acc = 0.f;
#pragma unroll
    for (int k = 0; k < 64; ++k)
        acc = fmaf(__shfl(pv, k, 64), Ws[k * 64 + lane], acc);
    H[wave * 64 + lane] = fmaxf(fmaf(acc, scale, shift), 0.f);
}

// ---------- pooling + head ----------

__global__ __launch_bounds__(256) void k_pool(const float* __restrict__ h,
                                              const int* __restrict__ batch,
                                              float* __restrict__ sums,
                                              float* __restrict__ cnts) {
    const int CHUNK = 32;
    int gw = (blockIdx.x * 256 + threadIdx.x) >> 6;
    int lane = threadIdx.x & 63;
    int nw = (gridDim.x * 256) >> 6;
    int nchunks = (NN + CHUNK - 1) / CHUNK;
    for (int c = gw; c < nchunks; c += nw) {
        int n0 = c * CHUNK;
        int n1 = min(n0 + CHUNK, NN);
        int gcur = batch[n0];
        float accf = 0.f;
        float cntf = 0.f;
        for (int n = n0; n < n1; ++n) {
            int gg = batch[n];
            if (gg != gcur) {
                atomicAdd(&sums[gcur * 64 + lane], accf);
                if (lane == 0) atomicAdd(&cnts[gcur], cntf);
                accf = 0.f;
                cntf = 0.f;
                gcur = gg;
            }
            accf += h[n * 64 + lane];
            cntf += 1.f;
        }
        atomicAdd(&sums[gcur * 64 + lane], accf);
        if (lane == 0) atomicAdd(&cnts[gcur], cntf);
    }
}

__global__ __launch_bounds__(256) void k_head(const float* __restrict__ sums,
                                              const float* __restrict__ cnts,
                                              const float* __restrict__ Wr1,
                                              const float* __restrict__ br1,
                                              const float* __restrict__ Wr2,
                                              const float* __restrict__ br2,
                                              float* __restrict__ out) {
    int wave = (blockIdx.x * 256 + threadIdx.x) >> 6;
    int lane = threadIdx.x & 63;
    if (wave >= NG) return;
    float c = fmaxf(cnts[wave], 1.0f);
    float pooled = sums[wave * 64 + lane] / c;
    float acc = 0.f;
#pragma unroll
    for (int k = 0; k < 64; ++k)
        acc = fmaf(__shfl(pooled, k, 64), Wr1[k * 64 + lane], acc);
    float hid = fmaxf(acc + br1[lane], 0.f);
    float o0 = hid * Wr2[lane * 2 + 0];
    float o1 = hid * Wr2[lane * 2 + 1];
#pragma unroll
    for (int off = 32; off > 0; off >>= 1) {
        o0 += __shfl_xor(o0, off, 64);
        o1 += __shfl_xor(o1, off, 64);
    }
    if (lane == 0) {
        out[wave * 2 + 0] = o0 + br2[0];
        out[wave * 2 + 1] = o1 + br2[1];
    }
}

extern "C" void kernel_launch(void* const* d_in, const int* in_sizes, int n_in,
                              void* d_out, int out_size, void* d_ws, size_t ws_size,
                              hipStream_t stream) {
    const float* x   = (const float*)d_in[0];
    const int*   ei  = (const int*)d_in[1];     // [2, E]: row0=src, row1=dst
    const int*   bat = (const int*)d_in[2];
    const float* W1  = (const float*)d_in[3];
    const float* b1  = (const float*)d_in[4];
    const float* g1  = (const float*)d_in[5];
    const float* be1 = (const float*)d_in[6];
    const float* rm1 = (const float*)d_in[7];
    const float* rv1 = (const float*)d_in[8];
    const float* W2  = (const float*)d_in[9];
    const float* b2  = (const float*)d_in[10];
    const float* g2  = (const float*)d_in[11];
    const float* be2 = (const float*)d_in[12];
    const float* rm2 = (const float*)d_in[13];
    const float* rv2 = (const float*)d_in[14];
    const float* W3  = (const float*)d_in[15];
    const float* b3  = (const float*)d_in[16];
    const float* g3  = (const float*)d_in[17];
    const float* be3 = (const float*)d_in[18];
    const float* rm3 = (const float*)d_in[19];
    const float* rv3 = (const float*)d_in[20];
    const float* Wr1 = (const float*)d_in[21];
    const float* br1 = (const float*)d_in[22];
    const float* Wr2 = (const float*)d_in[23];
    const float* br2 = (const float*)d_in[24];
    float* out = (float*)d_out;

    // workspace layout (4-byte words)
    int*   cnt    = (int*)d_ws;              // NN
    int*   rowptr = cnt + NN;                // NN
    int*   cursor = rowptr + NN;             // NN
    int*   bsum   = cursor + NN;             // 512
    float* dinv   = (float*)(bsum + 512);    // NN
    int2*  csr    = (int2*)(dinv + NN);      // NE int2 (2*NE words)
    float* P      = (float*)(csr + NE);      // NF (layer-1 uses first NN*8)
    float* H      = P + NF;                  // NF
    float* sums   = H + NF;                  // NG*64
    float* cnts   = sums + NG * 64;          // NG

    const int* srcI = ei;
    const int* dstI = ei + NE;

    const int gE = ceil_div(NE, 256);
    const int gN = ceil_div(NN, 256);       // 391
    const int gW = ceil_div(NN * 64, 256);  // wave-per-node kernels

    // CSR build (once; reused by all 3 layers)
    hipMemsetAsync(cnt, 0, NN * sizeof(int), stream);
    hipMemsetAsync(sums, 0, (NG * 64 + NG) * sizeof(float), stream);
    k_hist<<<gE, 256, 0, stream>>>(dstI, cnt);
    k_dinv<<<gN, 256, 0, stream>>>(cnt, dinv);
    k_scan1<<<gN, 256, 0, stream>>>(cnt, bsum);
    k_scan2<<<1, 512, 0, stream>>>(bsum, gN);
    k_scan3<<<gN, 256, 0, stream>>>(cnt, bsum, rowptr, cursor);
    k_fill<<<gE, 256, 0, stream>>>(srcI, dstI, dinv, cursor, csr);

    // layer 1: aggregate x (8-wide) then transform 8->64 + BN + ReLU
    k_gather8<<<gW, 256, 0, stream>>>(x, rowptr, cnt, dinv, csr, P);
    k_xf8bn<<<gW, 256, 0, stream>>>(P, W1, b1, g1, be1, rm1, rv1, H);

    // layer 2
    k_gather64<<<gW, 256, 0, stream>>>(H, rowptr, cnt, dinv, csr, P);
    k_xf64bn<<<gW, 256, 0, stream>>>(P, W2, b2, g2, be2, rm2, rv2, H);

    // layer 3
    k_gather64<<<gW, 256, 0, stream>>>(H, rowptr, cnt, dinv, csr, P);
    k_xf64bn<<<gW, 256, 0, stream>>>(P, W3, b3, g3, be3, rm3, rv3, H);

    // mean pool + head
    k_pool<<<800, 256, 0, stream>>>(H, bat, sums, cnts);
    k_head<<<ceil_div(NG * 64, 256), 256, 0, stream>>>(sums, cnts, Wr1, br1, Wr2, br2, out);
}

// Round 3
// 978.370 us; speedup vs baseline: 2.6027x; 1.0334x over previous
//
#include <hip/hip_runtime.h>

#define NN 100000
#define NE 3200000
#define NG 256
#define NF (NN * 64)
#define FEPS 1e-5f

static inline int ceil_div(int a, int b) { return (a + b - 1) / b; }

// ---------- CSR build ----------

__global__ __launch_bounds__(256) void k_hist(const int* __restrict__ dst,
                                              int* __restrict__ cnt) {
    int e = blockIdx.x * 256 + threadIdx.x;
    if (e < NE) atomicAdd(&cnt[dst[e]], 1);
}

// dinv[i] = rsqrt(in_deg + 1); xs[i,:] = x[i,:] * dinv[i]  (pre-scaled input)
__global__ __launch_bounds__(256) void k_dinv_xs(const int* __restrict__ cnt,
                                                 const float* __restrict__ x,
                                                 float* __restrict__ dinv,
                                                 float* __restrict__ xs) {
    int i = blockIdx.x * 256 + threadIdx.x;
    if (i >= NN) return;
    float di = rsqrtf((float)cnt[i] + 1.0f);
    dinv[i] = di;
#pragma unroll
    for (int f = 0; f < 8; ++f) xs[i * 8 + f] = x[i * 8 + f] * di;
}

__global__ __launch_bounds__(256) void k_scan1(const int* __restrict__ cnt,
                                               int* __restrict__ bsum) {
    __shared__ int s[256];
    int t = threadIdx.x;
    int i = blockIdx.x * 256 + t;
    s[t] = (i < NN) ? cnt[i] : 0;
    __syncthreads();
    for (int off = 128; off > 0; off >>= 1) {
        if (t < off) s[t] += s[t + off];
        __syncthreads();
    }
    if (t == 0) bsum[blockIdx.x] = s[0];
}

__global__ __launch_bounds__(512) void k_scan2(int* __restrict__ bsum, int nb) {
    __shared__ int s[512];
    int t = threadIdx.x;
    int v = (t < nb) ? bsum[t] : 0;
    s[t] = v;
    __syncthreads();
    for (int off = 1; off < 512; off <<= 1) {
        int add = (t >= off) ? s[t - off] : 0;
        __syncthreads();
        s[t] += add;
        __syncthreads();
    }
    if (t < nb) bsum[t] = s[t] - v;   // exclusive
}

__global__ __launch_bounds__(256) void k_scan3(const int* __restrict__ cnt,
                                               const int* __restrict__ bsum,
                                               int* __restrict__ rowptr,
                                               int* __restrict__ cursor) {
    __shared__ int s[256];
    int t = threadIdx.x;
    int i = blockIdx.x * 256 + t;
    int v = (i < NN) ? cnt[i] : 0;
    s[t] = v;
    __syncthreads();
    for (int off = 1; off < 256; off <<= 1) {
        int add = (t >= off) ? s[t - off] : 0;
        __syncthreads();
        s[t] += add;
        __syncthreads();
    }
    int ex = s[t] - v + bsum[blockIdx.x];
    if (i < NN) {
        rowptr[i] = ex;
        cursor[i] = ex;
    }
}

// CSR record = src index only (4B); norm handled by pre/post scaling.
__global__ __launch_bounds__(256) void k_fill(const int* __restrict__ src,
                                              const int* __restrict__ dst,
                                              int* __restrict__ cursor,
                                              int* __restrict__ csr) {
    int e = blockIdx.x * 256 + threadIdx.x;
    if (e >= NE) return;
    int s = src[e];
    int d = dst[e];
    int pos = atomicAdd(&cursor[d], 1);
    csr[pos] = s;
}

// ---------- fused gather + transform + BN + ReLU (+ dinv scale) ----------

// Layer 1: aggregate xs (8-wide), transform 8->64, BN, ReLU, scale by dinv.
__global__ __launch_bounds__(256) void k_gxf8(const float* __restrict__ xs,
                                              const int* __restrict__ rowptr,
                                              const int* __restrict__ cnt,
                                              const float* __restrict__ dinv,
                                              const int* __restrict__ csr,
                                              const float* __restrict__ W,
                                              const float* __restrict__ b,
                                              const float* __restrict__ g,
                                              const float* __restrict__ be,
                                              const float* __restrict__ rm,
                                              const float* __restrict__ rv,
                                              float* __restrict__ out) {
    __shared__ float Ws[512];
    int tid = threadIdx.x;
    for (int i = tid; i < 512; i += 256) Ws[i] = W[i];
    __syncthreads();
    int wave = (blockIdx.x * 256 + tid) >> 6;
    int lane = tid & 63;
    if (wave >= NN) return;
    int es = lane >> 3, f = lane & 7;
    int st = rowptr[wave], n = cnt[wave];
    float acc = 0.f;
    for (int k0 = 0; k0 < n; k0 += 8) {
        int kk = k0 + es;
        if (kk < n) acc += xs[csr[st + kk] * 8 + f];
    }
    // xor-reduce across edge-sub groups; every lane ends with full sum for f
    acc += __shfl_xor(acc, 8, 64);
    acc += __shfl_xor(acc, 16, 64);
    acc += __shfl_xor(acc, 32, 64);
    float di = dinv[wave];
    float pf = (acc + xs[wave * 8 + f]) * di;    // aggregated feature f
    float scale = g[lane] * rsqrtf(rv[lane] + FEPS);
    float shift = be[lane] + (b[lane] - rm[lane]) * scale;
    float o = 0.f;
#pragma unroll
    for (int k = 0; k < 8; ++k)
        o = fmaf(__shfl(pf, k, 64), Ws[k * 64 + lane], o);
    o = fmaxf(fmaf(o, scale, shift), 0.f);
    out[wave * 64 + lane] = o * di;              // pre-scale for next layer
}

// Layers 2/3: aggregate Hs (64-wide), transform 64->64, BN, ReLU,
// optionally scale output by dinv (layer 3 output feeds pooling unscaled).
template <bool SCALE_OUT>
__global__ __launch_bounds__(256) void k_gxf64(const float* __restrict__ Hin,
                                               const int* __restrict__ rowptr,
                                               const int* __restrict__ cnt,
                                               const float* __restrict__ dinv,
                                               const int* __restrict__ csr,
                                               const float* __restrict__ W,
                                               const float* __restrict__ b,
                                               const float* __restrict__ g,
                                               const float* __restrict__ be,
                                               const float* __restrict__ rm,
                                               const float* __restrict__ rv,
                                               float* __restrict__ out) {
    __shared__ float Ws[4096];
    int tid = threadIdx.x;
    for (int i = tid; i < 4096; i += 256) Ws[i] = W[i];
    __syncthreads();
    int wave = (blockIdx.x * 256 + tid) >> 6;
    int lane = tid & 63;
    if (wave >= NN) return;
    int st = rowptr[wave], n = cnt[wave];
    float acc = Hin[wave * 64 + lane];           // self-loop (Hin pre-scaled)
    int k = 0;
    for (; k + 4 <= n; k += 4) {
        int s0 = csr[st + k];
        int s1 = csr[st + k + 1];
        int s2 = csr[st + k + 2];
        int s3 = csr[st + k + 3];
        float v0 = Hin[s0 * 64 + lane];
        float v1 = Hin[s1 * 64 + lane];
        float v2 = Hin[s2 * 64 + lane];
        float v3 = Hin[s3 * 64 + lane];
        acc += v0; acc += v1; acc += v2; acc += v3;
    }
    for (; k < n; ++k) acc += Hin[csr[st + k] * 64 + lane];
    float di = dinv[wave];
    float pf = acc * di;                          // aggregated feature `lane`
    float scale = g[lane] * rsqrtf(rv[lane] + FEPS);
    float shift = be[lane] + (b[lane] - rm[lane]) * scale;
    float o = 0.f;
#pragma unroll
    for (int k2 = 0; k2 < 64; ++k2)
        o = fmaf(__shfl(pf, k2, 64), Ws[k2 * 64 + lane], o);
    o = fmaxf(fmaf(o, scale, shift), 0.f);
    if (SCALE_OUT) o *= di;
    out[wave * 64 + lane] = o;
}

// ---------- pooling + head ----------

__global__ __launch_bounds__(256) void k_pool(const float* __restrict__ h,
                                              const int* __restrict__ batch,
                                              float* __restrict__ sums,
                                              float* __restrict__ cnts) {
    const int CHUNK = 32;
    int gw = (blockIdx.x * 256 + threadIdx.x) >> 6;
    int lane = threadIdx.x & 63;
    int nw = (gridDim.x * 256) >> 6;
    int nchunks = (NN + CHUNK - 1) / CHUNK;
    for (int c = gw; c < nchunks; c += nw) {
        int n0 = c * CHUNK;
        int n1 = min(n0 + CHUNK, NN);
        int gcur = batch[n0];
        float accf = 0.f;
        float cntf = 0.f;
        for (int n = n0; n < n1; ++n) {
            int gg = batch[n];
            if (gg != gcur) {
                atomicAdd(&sums[gcur * 64 + lane], accf);
                if (lane == 0) atomicAdd(&cnts[gcur], cntf);
                accf = 0.f;
                cntf = 0.f;
                gcur = gg;
            }
            accf += h[n * 64 + lane];
            cntf += 1.f;
        }
        atomicAdd(&sums[gcur * 64 + lane], accf);
        if (lane == 0) atomicAdd(&cnts[gcur], cntf);
    }
}

__global__ __launch_bounds__(256) void k_head(const float* __restrict__ sums,
                                              const float* __restrict__ cnts,
                                              const float* __restrict__ Wr1,
                                              const float* __restrict__ br1,
                                              const float* __restrict__ Wr2,
                                              const float* __restrict__ br2,
                                              float* __restrict__ out) {
    int wave = (blockIdx.x * 256 + threadIdx.x) >> 6;
    int lane = threadIdx.x & 63;
    if (wave >= NG) return;
    float c = fmaxf(cnts[wave], 1.0f);
    float pooled = sums[wave * 64 + lane] / c;
    float acc = 0.f;
#pragma unroll
    for (int k = 0; k < 64; ++k)
        acc = fmaf(__shfl(pooled, k, 64), Wr1[k * 64 + lane], acc);
    float hid = fmaxf(acc + br1[lane], 0.f);
    float o0 = hid * Wr2[lane * 2 + 0];
    float o1 = hid * Wr2[lane * 2 + 1];
#pragma unroll
    for (int off = 32; off > 0; off >>= 1) {
        o0 += __shfl_xor(o0, off, 64);
        o1 += __shfl_xor(o1, off, 64);
    }
    if (lane == 0) {
        out[wave * 2 + 0] = o0 + br2[0];
        out[wave * 2 + 1] = o1 + br2[1];
    }
}

extern "C" void kernel_launch(void* const* d_in, const int* in_sizes, int n_in,
                              void* d_out, int out_size, void* d_ws, size_t ws_size,
                              hipStream_t stream) {
    const float* x   = (const float*)d_in[0];
    const int*   ei  = (const int*)d_in[1];     // [2, E]: row0=src, row1=dst
    const int*   bat = (const int*)d_in[2];
    const float* W1  = (const float*)d_in[3];
    const float* b1  = (const float*)d_in[4];
    const float* g1  = (const float*)d_in[5];
    const float* be1 = (const float*)d_in[6];
    const float* rm1 = (const float*)d_in[7];
    const float* rv1 = (const float*)d_in[8];
    const float* W2  = (const float*)d_in[9];
    const float* b2  = (const float*)d_in[10];
    const float* g2  = (const float*)d_in[11];
    const float* be2 = (const float*)d_in[12];
    const float* rm2 = (const float*)d_in[13];
    const float* rv2 = (const float*)d_in[14];
    const float* W3  = (const float*)d_in[15];
    const float* b3  = (const float*)d_in[16];
    const float* g3  = (const float*)d_in[17];
    const float* be3 = (const float*)d_in[18];
    const float* rm3 = (const float*)d_in[19];
    const float* rv3 = (const float*)d_in[20];
    const float* Wr1 = (const float*)d_in[21];
    const float* br1 = (const float*)d_in[22];
    const float* Wr2 = (const float*)d_in[23];
    const float* br2 = (const float*)d_in[24];
    float* out = (float*)d_out;

    // workspace layout (4-byte words)
    int*   cnt    = (int*)d_ws;              // NN
    int*   rowptr = cnt + NN;                // NN
    int*   cursor = rowptr + NN;             // NN
    int*   bsum   = cursor + NN;             // 512
    float* dinv   = (float*)(bsum + 512);    // NN
    int*   csr    = (int*)(dinv + NN);       // NE
    float* xs     = (float*)(csr + NE);      // NN*8
    float* A      = xs + NN * 8;             // NF
    float* B      = A + NF;                  // NF
    float* sums   = B + NF;                  // NG*64
    float* cnts   = sums + NG * 64;          // NG

    const int* srcI = ei;
    const int* dstI = ei + NE;

    const int gE = ceil_div(NE, 256);
    const int gN = ceil_div(NN, 256);       // 391
    const int gW = ceil_div(NN * 64, 256);  // wave-per-node kernels

    hipMemsetAsync(cnt, 0, NN * sizeof(int), stream);
    hipMemsetAsync(sums, 0, (NG * 64 + NG) * sizeof(float), stream);

    // CSR build (src-only records)
    k_hist<<<gE, 256, 0, stream>>>(dstI, cnt);
    k_dinv_xs<<<gN, 256, 0, stream>>>(cnt, x, dinv, xs);
    k_scan1<<<gN, 256, 0, stream>>>(cnt, bsum);
    k_scan2<<<1, 512, 0, stream>>>(bsum, gN);
    k_scan3<<<gN, 256, 0, stream>>>(cnt, bsum, rowptr, cursor);
    k_fill<<<gE, 256, 0, stream>>>(srcI, dstI, cursor, csr);

    // layer 1: gather(xs) + 8->64 xform + BN + ReLU -> A (pre-scaled)
    k_gxf8<<<gW, 256, 0, stream>>>(xs, rowptr, cnt, dinv, csr,
                                   W1, b1, g1, be1, rm1, rv1, A);
    // layer 2: gather(A) + xform + BN + ReLU -> B (pre-scaled)
    k_gxf64<true><<<gW, 256, 0, stream>>>(A, rowptr, cnt, dinv, csr,
                                          W2, b2, g2, be2, rm2, rv2, B);
    // layer 3: gather(B) + xform + BN + ReLU -> A (unscaled, for pooling)
    k_gxf64<false><<<gW, 256, 0, stream>>>(B, rowptr, cnt, dinv, csr,
                                           W3, b3, g3, be3, rm3, rv3, A);

    // mean pool + head
    k_pool<<<800, 256, 0, stream>>>(A, bat, sums, cnts);
    k_head<<<ceil_div(NG * 64, 256), 256, 0, stream>>>(sums, cnts, Wr1, br1, Wr2, br2, out);
}

// Round 4
// 701.913 us; speedup vs baseline: 3.6278x; 1.3939x over previous
//
#include <hip/hip_runtime.h>

#define NN 100000
#define NE 3200000
#define NG 256
#define NF (NN * 64)
#define FEPS 1e-5f
#define BSH 8                       // 256 dst-nodes per bucket
#define NB ((NN + 255) >> 8)        // 391 buckets
#define CHA 8192                    // edges per block in pass A

static inline int ceil_div(int a, int b) { return (a + b - 1) / b; }

// ---------- pass A: coarse bucket partition of edges ----------

__global__ __launch_bounds__(256) void kA_hist(const int* __restrict__ dst,
                                               int* __restrict__ bh) {
    __shared__ int lh[NB];
    int t = threadIdx.x;
    for (int b = t; b < NB; b += 256) lh[b] = 0;
    __syncthreads();
    int e0 = blockIdx.x * CHA;
    int e1 = min(e0 + CHA, NE);
    for (int i = e0 + t; i < e1; i += 256) atomicAdd(&lh[dst[i] >> BSH], 1);
    __syncthreads();
    for (int b = t; b < NB; b += 256)
        if (lh[b]) atomicAdd(&bh[b], lh[b]);
}

// exclusive scan of bh[NB] -> bboff (and bcur copy); single block
__global__ __launch_bounds__(512) void kA_scan(const int* __restrict__ bh,
                                               int* __restrict__ bboff,
                                               int* __restrict__ bcur) {
    __shared__ int s[512];
    int t = threadIdx.x;
    int v = (t < NB) ? bh[t] : 0;
    s[t] = v;
    __syncthreads();
    for (int off = 1; off < 512; off <<= 1) {
        int add = (t >= off) ? s[t - off] : 0;
        __syncthreads();
        s[t] += add;
        __syncthreads();
    }
    if (t < NB) {
        int ex = s[t] - v;
        bboff[t] = ex;
        bcur[t] = ex;
    }
    if (t == 0) bboff[NB] = NE;
}

// append (src,dst) records into bucket regions; per-block reserve + LDS cursors
__global__ __launch_bounds__(256) void kA_fill(const int* __restrict__ src,
                                               const int* __restrict__ dst,
                                               int* __restrict__ bcur,
                                               int2* __restrict__ ebuf) {
    __shared__ int lh[NB];
    __shared__ int lbase[NB];
    __shared__ int lcur[NB];
    int t = threadIdx.x;
    for (int b = t; b < NB; b += 256) lh[b] = 0;
    __syncthreads();
    int e0 = blockIdx.x * CHA;
    int e1 = min(e0 + CHA, NE);
    for (int i = e0 + t; i < e1; i += 256) atomicAdd(&lh[dst[i] >> BSH], 1);
    __syncthreads();
    for (int b = t; b < NB; b += 256) {
        int c = lh[b];
        lbase[b] = c ? atomicAdd(&bcur[b], c) : 0;
        lcur[b] = 0;
    }
    __syncthreads();
    for (int i = e0 + t; i < e1; i += 256) {
        int d = dst[i];
        int s = src[i];
        int b = d >> BSH;
        int p = atomicAdd(&lcur[b], 1);
        ebuf[lbase[b] + p] = make_int2(s, d);
    }
}

// ---------- pass B: per-bucket node hist + CSR fill ----------

// node in-degree counts via LDS (one block per bucket)
__global__ __launch_bounds__(256) void kB_hist(const int2* __restrict__ ebuf,
                                               const int* __restrict__ bboff,
                                               int* __restrict__ cnt) {
    __shared__ int lc[256];
    int b = blockIdx.x;
    int t = threadIdx.x;
    lc[t] = 0;
    __syncthreads();
    int st = bboff[b], en = bboff[b + 1];
    for (int i = st + t; i < en; i += 256) atomicAdd(&lc[ebuf[i].y & 255], 1);
    __syncthreads();
    int node = (b << BSH) + t;
    if (node < NN) cnt[node] = lc[t];
}

// dinv[i] = rsqrt(in_deg + 1); xs[i,:] = x[i,:] * dinv[i]
__global__ __launch_bounds__(256) void k_dinv_xs(const int* __restrict__ cnt,
                                                 const float* __restrict__ x,
                                                 float* __restrict__ dinv,
                                                 float* __restrict__ xs) {
    int i = blockIdx.x * 256 + threadIdx.x;
    if (i >= NN) return;
    float di = rsqrtf((float)cnt[i] + 1.0f);
    dinv[i] = di;
#pragma unroll
    for (int f = 0; f < 8; ++f) xs[i * 8 + f] = x[i * 8 + f] * di;
}

// hierarchical exclusive scan of cnt[NN] -> rowptr[NN]
__global__ __launch_bounds__(256) void k_scan1(const int* __restrict__ cnt,
                                               int* __restrict__ bsum) {
    __shared__ int s[256];
    int t = threadIdx.x;
    int i = blockIdx.x * 256 + t;
    s[t] = (i < NN) ? cnt[i] : 0;
    __syncthreads();
    for (int off = 128; off > 0; off >>= 1) {
        if (t < off) s[t] += s[t + off];
        __syncthreads();
    }
    if (t == 0) bsum[blockIdx.x] = s[0];
}

__global__ __launch_bounds__(512) void k_scan2(int* __restrict__ bsum, int nb) {
    __shared__ int s[512];
    int t = threadIdx.x;
    int v = (t < nb) ? bsum[t] : 0;
    s[t] = v;
    __syncthreads();
    for (int off = 1; off < 512; off <<= 1) {
        int add = (t >= off) ? s[t - off] : 0;
        __syncthreads();
        s[t] += add;
        __syncthreads();
    }
    if (t < nb) bsum[t] = s[t] - v;   // exclusive
}

__global__ __launch_bounds__(256) void k_scan3(const int* __restrict__ cnt,
                                               const int* __restrict__ bsum,
                                               int* __restrict__ rowptr) {
    __shared__ int s[256];
    int t = threadIdx.x;
    int i = blockIdx.x * 256 + t;
    int v = (i < NN) ? cnt[i] : 0;
    s[t] = v;
    __syncthreads();
    for (int off = 1; off < 256; off <<= 1) {
        int add = (t >= off) ? s[t - off] : 0;
        __syncthreads();
        s[t] += add;
        __syncthreads();
    }
    if (i < NN) rowptr[i] = s[t] - v + bsum[blockIdx.x];
}

// final CSR fill: one block per bucket; writes land in a contiguous region
__global__ __launch_bounds__(256) void kB_fill(const int2* __restrict__ ebuf,
                                               const int* __restrict__ bboff,
                                               const int* __restrict__ rowptr,
                                               int* __restrict__ csr) {
    __shared__ int rp[256];
    __shared__ int lc[256];
    int b = blockIdx.x;
    int t = threadIdx.x;
    int node = (b << BSH) + t;
    rp[t] = (node < NN) ? rowptr[node] : 0;
    lc[t] = 0;
    __syncthreads();
    int st = bboff[b], en = bboff[b + 1];
    for (int i = st + t; i < en; i += 256) {
        int2 e = ebuf[i];
        int dl = e.y & 255;
        int p = atomicAdd(&lc[dl], 1);
        csr[rp[dl] + p] = e.x;
    }
}

// ---------- fused gather + transform + BN + ReLU (+ dinv scale) ----------

__global__ __launch_bounds__(256) void k_gxf8(const float* __restrict__ xs,
                                              const int* __restrict__ rowptr,
                                              const int* __restrict__ cnt,
                                              const float* __restrict__ dinv,
                                              const int* __restrict__ csr,
                                              const float* __restrict__ W,
                                              const float* __restrict__ b,
                                              const float* __restrict__ g,
                                              const float* __restrict__ be,
                                              const float* __restrict__ rm,
                                              const float* __restrict__ rv,
                                              float* __restrict__ out) {
    __shared__ float Ws[512];
    int tid = threadIdx.x;
    for (int i = tid; i < 512; i += 256) Ws[i] = W[i];
    __syncthreads();
    int wave = (blockIdx.x * 256 + tid) >> 6;
    int lane = tid & 63;
    if (wave >= NN) return;
    int es = lane >> 3, f = lane & 7;
    int st = rowptr[wave], n = cnt[wave];
    float acc = 0.f;
    for (int k0 = 0; k0 < n; k0 += 8) {
        int kk = k0 + es;
        if (kk < n) acc += xs[csr[st + kk] * 8 + f];
    }
    acc += __shfl_xor(acc, 8, 64);
    acc += __shfl_xor(acc, 16, 64);
    acc += __shfl_xor(acc, 32, 64);
    float di = dinv[wave];
    float pf = (acc + xs[wave * 8 + f]) * di;
    float scale = g[lane] * rsqrtf(rv[lane] + FEPS);
    float shift = be[lane] + (b[lane] - rm[lane]) * scale;
    float o = 0.f;
#pragma unroll
    for (int k = 0; k < 8; ++k)
        o = fmaf(__shfl(pf, k, 64), Ws[k * 64 + lane], o);
    o = fmaxf(fmaf(o, scale, shift), 0.f);
    out[wave * 64 + lane] = o * di;
}

template <bool SCALE_OUT>
__global__ __launch_bounds__(256) void k_gxf64(const float* __restrict__ Hin,
                                               const int* __restrict__ rowptr,
                                               const int* __restrict__ cnt,
                                               const float* __restrict__ dinv,
                                               const int* __restrict__ csr,
                                               const float* __restrict__ W,
                                               const float* __restrict__ b,
                                               const float* __restrict__ g,
                                               const float* __restrict__ be,
                                               const float* __restrict__ rm,
                                               const float* __restrict__ rv,
                                               float* __restrict__ out) {
    __shared__ float Ws[4096];
    int tid = threadIdx.x;
    for (int i = tid; i < 4096; i += 256) Ws[i] = W[i];
    __syncthreads();
    int wave = (blockIdx.x * 256 + tid) >> 6;
    int lane = tid & 63;
    if (wave >= NN) return;
    int st = rowptr[wave], n = cnt[wave];
    float acc = Hin[wave * 64 + lane];           // self-loop (Hin pre-scaled)
    int k = 0;
    for (; k + 4 <= n; k += 4) {
        int s0 = csr[st + k];
        int s1 = csr[st + k + 1];
        int s2 = csr[st + k + 2];
        int s3 = csr[st + k + 3];
        float v0 = Hin[s0 * 64 + lane];
        float v1 = Hin[s1 * 64 + lane];
        float v2 = Hin[s2 * 64 + lane];
        float v3 = Hin[s3 * 64 + lane];
        acc += v0; acc += v1; acc += v2; acc += v3;
    }
    for (; k < n; ++k) acc += Hin[csr[st + k] * 64 + lane];
    float di = dinv[wave];
    float pf = acc * di;
    float scale = g[lane] * rsqrtf(rv[lane] + FEPS);
    float shift = be[lane] + (b[lane] - rm[lane]) * scale;
    float o = 0.f;
#pragma unroll
    for (int k2 = 0; k2 < 64; ++k2)
        o = fmaf(__shfl(pf, k2, 64), Ws[k2 * 64 + lane], o);
    o = fmaxf(fmaf(o, scale, shift), 0.f);
    if (SCALE_OUT) o *= di;
    out[wave * 64 + lane] = o;
}

// ---------- pooling + head ----------

__global__ __launch_bounds__(256) void k_pool(const float* __restrict__ h,
                                              const int* __restrict__ batch,
                                              float* __restrict__ sums,
                                              float* __restrict__ cnts) {
    const int CHUNK = 32;
    int gw = (blockIdx.x * 256 + threadIdx.x) >> 6;
    int lane = threadIdx.x & 63;
    int nw = (gridDim.x * 256) >> 6;
    int nchunks = (NN + CHUNK - 1) / CHUNK;
    for (int c = gw; c < nchunks; c += nw) {
        int n0 = c * CHUNK;
        int n1 = min(n0 + CHUNK, NN);
        int gcur = batch[n0];
        float accf = 0.f;
        float cntf = 0.f;
        for (int n = n0; n < n1; ++n) {
            int gg = batch[n];
            if (gg != gcur) {
                atomicAdd(&sums[gcur * 64 + lane], accf);
                if (lane == 0) atomicAdd(&cnts[gcur], cntf);
                accf = 0.f;
                cntf = 0.f;
                gcur = gg;
            }
            accf += h[n * 64 + lane];
            cntf += 1.f;
        }
        atomicAdd(&sums[gcur * 64 + lane], accf);
        if (lane == 0) atomicAdd(&cnts[gcur], cntf);
    }
}

__global__ __launch_bounds__(256) void k_head(const float* __restrict__ sums,
                                              const float* __restrict__ cnts,
                                              const float* __restrict__ Wr1,
                                              const float* __restrict__ br1,
                                              const float* __restrict__ Wr2,
                                              const float* __restrict__ br2,
                                              float* __restrict__ out) {
    int wave = (blockIdx.x * 256 + threadIdx.x) >> 6;
    int lane = threadIdx.x & 63;
    if (wave >= NG) return;
    float c = fmaxf(cnts[wave], 1.0f);
    float pooled = sums[wave * 64 + lane] / c;
    float acc = 0.f;
#pragma unroll
    for (int k = 0; k < 64; ++k)
        acc = fmaf(__shfl(pooled, k, 64), Wr1[k * 64 + lane], acc);
    float hid = fmaxf(acc + br1[lane], 0.f);
    float o0 = hid * Wr2[lane * 2 + 0];
    float o1 = hid * Wr2[lane * 2 + 1];
#pragma unroll
    for (int off = 32; off > 0; off >>= 1) {
        o0 += __shfl_xor(o0, off, 64);
        o1 += __shfl_xor(o1, off, 64);
    }
    if (lane == 0) {
        out[wave * 2 + 0] = o0 + br2[0];
        out[wave * 2 + 1] = o1 + br2[1];
    }
}

extern "C" void kernel_launch(void* const* d_in, const int* in_sizes, int n_in,
                              void* d_out, int out_size, void* d_ws, size_t ws_size,
                              hipStream_t stream) {
    const float* x   = (const float*)d_in[0];
    const int*   ei  = (const int*)d_in[1];     // [2, E]: row0=src, row1=dst
    const int*   bat = (const int*)d_in[2];
    const float* W1  = (const float*)d_in[3];
    const float* b1  = (const float*)d_in[4];
    const float* g1  = (const float*)d_in[5];
    const float* be1 = (const float*)d_in[6];
    const float* rm1 = (const float*)d_in[7];
    const float* rv1 = (const float*)d_in[8];
    const float* W2  = (const float*)d_in[9];
    const float* b2  = (const float*)d_in[10];
    const float* g2  = (const float*)d_in[11];
    const float* be2 = (const float*)d_in[12];
    const float* rm2 = (const float*)d_in[13];
    const float* rv2 = (const float*)d_in[14];
    const float* W3  = (const float*)d_in[15];
    const float* b3  = (const float*)d_in[16];
    const float* g3  = (const float*)d_in[17];
    const float* be3 = (const float*)d_in[18];
    const float* rm3 = (const float*)d_in[19];
    const float* rv3 = (const float*)d_in[20];
    const float* Wr1 = (const float*)d_in[21];
    const float* br1 = (const float*)d_in[22];
    const float* Wr2 = (const float*)d_in[23];
    const float* br2 = (const float*)d_in[24];
    float* out = (float*)d_out;

    // workspace layout (4-byte words)
    int*   cnt    = (int*)d_ws;               // NN
    int*   rowptr = cnt + NN;                 // NN
    int*   bsum   = rowptr + NN;              // 512
    int*   bh     = bsum + 512;               // NB
    int*   bboff  = bh + NB;                  // NB+1
    int*   bcur   = bboff + NB + 1;           // NB
    float* dinv   = (float*)(bcur + NB);      // NN
    int*   csr    = (int*)(dinv + NN);        // NE
    float* xs     = (float*)(csr + NE);       // NN*8
    float* A      = xs + NN * 8;              // NF
    float* B      = A + NF;                   // NF
    float* sums   = B + NF;                   // NG*64
    float* cnts   = sums + NG * 64;           // NG
    int2*  ebuf   = (int2*)A;                 // NE int2, aliases A (dead until layer 1)

    const int* srcI = ei;
    const int* dstI = ei + NE;

    const int gA = ceil_div(NE, CHA);        // 391
    const int gN = ceil_div(NN, 256);        // 391
    const int gW = ceil_div(NN * 64, 256);   // wave-per-node kernels

    hipMemsetAsync(bh, 0, NB * sizeof(int), stream);
    hipMemsetAsync(sums, 0, (NG * 64 + NG) * sizeof(float), stream);

    // pass A: bucket partition
    kA_hist<<<gA, 256, 0, stream>>>(dstI, bh);
    kA_scan<<<1, 512, 0, stream>>>(bh, bboff, bcur);
    kA_fill<<<gA, 256, 0, stream>>>(srcI, dstI, bcur, ebuf);

    // pass B: node counts, scan, CSR fill
    kB_hist<<<NB, 256, 0, stream>>>(ebuf, bboff, cnt);
    k_dinv_xs<<<gN, 256, 0, stream>>>(cnt, x, dinv, xs);
    k_scan1<<<gN, 256, 0, stream>>>(cnt, bsum);
    k_scan2<<<1, 512, 0, stream>>>(bsum, gN);
    k_scan3<<<gN, 256, 0, stream>>>(cnt, bsum, rowptr);
    kB_fill<<<NB, 256, 0, stream>>>(ebuf, bboff, rowptr, csr);

    // layers (fused gather + transform + BN + ReLU)
    k_gxf8<<<gW, 256, 0, stream>>>(xs, rowptr, cnt, dinv, csr,
                                   W1, b1, g1, be1, rm1, rv1, A);
    k_gxf64<true><<<gW, 256, 0, stream>>>(A, rowptr, cnt, dinv, csr,
                                          W2, b2, g2, be2, rm2, rv2, B);
    k_gxf64<false><<<gW, 256, 0, stream>>>(B, rowptr, cnt, dinv, csr,
                                           W3, b3, g3, be3, rm3, rv3, A);

    // mean pool + head
    k_pool<<<800, 256, 0, stream>>>(A, bat, sums, cnts);
    k_head<<<ceil_div(NG * 64, 256), 256, 0, stream>>>(sums, cnts, Wr1, br1, Wr2, br2, out);
}

// Round 5
// 648.582 us; speedup vs baseline: 3.9261x; 1.0822x over previous
//
#include <hip/hip_runtime.h>
#include <hip/hip_fp16.h>

#define NN 100000
#define NE 3200000
#define NG 256
#define NF (NN * 64)
#define FEPS 1e-5f
#define BSH 8                       // 256 dst-nodes per bucket
#define NB ((NN + 255) >> 8)        // 391 buckets
#define CHA 8192                    // edges per block in pass A

static inline int ceil_div(int a, int b) { return (a + b - 1) / b; }

// ---------- pass A: coarse bucket partition of edges ----------

__global__ __launch_bounds__(256) void kA_hist(const int* __restrict__ dst,
                                               int* __restrict__ bh) {
    __shared__ int lh[NB];
    int t = threadIdx.x;
    for (int b = t; b < NB; b += 256) lh[b] = 0;
    __syncthreads();
    int e0 = blockIdx.x * CHA;
    int e1 = min(e0 + CHA, NE);
    for (int i = e0 + t; i < e1; i += 256) atomicAdd(&lh[dst[i] >> BSH], 1);
    __syncthreads();
    for (int b = t; b < NB; b += 256)
        if (lh[b]) atomicAdd(&bh[b], lh[b]);
}

__global__ __launch_bounds__(512) void kA_scan(const int* __restrict__ bh,
                                               int* __restrict__ bboff,
                                               int* __restrict__ bcur) {
    __shared__ int s[512];
    int t = threadIdx.x;
    int v = (t < NB) ? bh[t] : 0;
    s[t] = v;
    __syncthreads();
    for (int off = 1; off < 512; off <<= 1) {
        int add = (t >= off) ? s[t - off] : 0;
        __syncthreads();
        s[t] += add;
        __syncthreads();
    }
    if (t < NB) {
        int ex = s[t] - v;
        bboff[t] = ex;
        bcur[t] = ex;
    }
    if (t == 0) bboff[NB] = NE;
}

__global__ __launch_bounds__(256) void kA_fill(const int* __restrict__ src,
                                               const int* __restrict__ dst,
                                               int* __restrict__ bcur,
                                               int2* __restrict__ ebuf) {
    __shared__ int lh[NB];
    __shared__ int lbase[NB];
    __shared__ int lcur[NB];
    int t = threadIdx.x;
    for (int b = t; b < NB; b += 256) lh[b] = 0;
    __syncthreads();
    int e0 = blockIdx.x * CHA;
    int e1 = min(e0 + CHA, NE);
    for (int i = e0 + t; i < e1; i += 256) atomicAdd(&lh[dst[i] >> BSH], 1);
    __syncthreads();
    for (int b = t; b < NB; b += 256) {
        int c = lh[b];
        lbase[b] = c ? atomicAdd(&bcur[b], c) : 0;
        lcur[b] = 0;
    }
    __syncthreads();
    for (int i = e0 + t; i < e1; i += 256) {
        int d = dst[i];
        int s = src[i];
        int b = d >> BSH;
        int p = atomicAdd(&lcur[b], 1);
        ebuf[lbase[b] + p] = make_int2(s, d);
    }
}

// ---------- pass B: per-bucket node hist + CSR fill ----------

__global__ __launch_bounds__(256) void kB_hist(const int2* __restrict__ ebuf,
                                               const int* __restrict__ bboff,
                                               int* __restrict__ cnt) {
    __shared__ int lc[256];
    int b = blockIdx.x;
    int t = threadIdx.x;
    lc[t] = 0;
    __syncthreads();
    int st = bboff[b], en = bboff[b + 1];
    for (int i = st + t; i < en; i += 256) atomicAdd(&lc[ebuf[i].y & 255], 1);
    __syncthreads();
    int node = (b << BSH) + t;
    if (node < NN) cnt[node] = lc[t];
}

// dinv[i] = rsqrt(in_deg + 1); xs[i,:] = fp16(x[i,:] * dinv[i])
__global__ __launch_bounds__(256) void k_dinv_xs(const int* __restrict__ cnt,
                                                 const float* __restrict__ x,
                                                 float* __restrict__ dinv,
                                                 __half* __restrict__ xs) {
    int i = blockIdx.x * 256 + threadIdx.x;
    if (i >= NN) return;
    float di = rsqrtf((float)cnt[i] + 1.0f);
    dinv[i] = di;
#pragma unroll
    for (int f = 0; f < 8; ++f) xs[i * 8 + f] = __float2half(x[i * 8 + f] * di);
}

__global__ __launch_bounds__(256) void k_scan1(const int* __restrict__ cnt,
                                               int* __restrict__ bsum) {
    __shared__ int s[256];
    int t = threadIdx.x;
    int i = blockIdx.x * 256 + t;
    s[t] = (i < NN) ? cnt[i] : 0;
    __syncthreads();
    for (int off = 128; off > 0; off >>= 1) {
        if (t < off) s[t] += s[t + off];
        __syncthreads();
    }
    if (t == 0) bsum[blockIdx.x] = s[0];
}

__global__ __launch_bounds__(512) void k_scan2(int* __restrict__ bsum, int nb) {
    __shared__ int s[512];
    int t = threadIdx.x;
    int v = (t < nb) ? bsum[t] : 0;
    s[t] = v;
    __syncthreads();
    for (int off = 1; off < 512; off <<= 1) {
        int add = (t >= off) ? s[t - off] : 0;
        __syncthreads();
        s[t] += add;
        __syncthreads();
    }
    if (t < nb) bsum[t] = s[t] - v;   // exclusive
}

__global__ __launch_bounds__(256) void k_scan3(const int* __restrict__ cnt,
                                               const int* __restrict__ bsum,
                                               int* __restrict__ rowptr) {
    __shared__ int s[256];
    int t = threadIdx.x;
    int i = blockIdx.x * 256 + t;
    int v = (i < NN) ? cnt[i] : 0;
    s[t] = v;
    __syncthreads();
    for (int off = 1; off < 256; off <<= 1) {
        int add = (t >= off) ? s[t - off] : 0;
        __syncthreads();
        s[t] += add;
        __syncthreads();
    }
    if (i < NN) rowptr[i] = s[t] - v + bsum[blockIdx.x];
}

__global__ __launch_bounds__(256) void kB_fill(const int2* __restrict__ ebuf,
                                               const int* __restrict__ bboff,
                                               const int* __restrict__ rowptr,
                                               int* __restrict__ csr) {
    __shared__ int rp[256];
    __shared__ int lc[256];
    int b = blockIdx.x;
    int t = threadIdx.x;
    int node = (b << BSH) + t;
    rp[t] = (node < NN) ? rowptr[node] : 0;
    lc[t] = 0;
    __syncthreads();
    int st = bboff[b], en = bboff[b + 1];
    for (int i = st + t; i < en; i += 256) {
        int2 e = ebuf[i];
        int dl = e.y & 255;
        int p = atomicAdd(&lc[dl], 1);
        csr[rp[dl] + p] = e.x;
    }
}

// ---------- fused gather + transform + BN + ReLU (+ dinv scale) ----------

// Layer 1: aggregate xs (8-wide fp16), transform 8->64, BN, ReLU, x dinv.
__global__ __launch_bounds__(256) void k_gxf8(const __half* __restrict__ xs,
                                              const int* __restrict__ rowptr,
                                              const int* __restrict__ cnt,
                                              const float* __restrict__ dinv,
                                              const int* __restrict__ csr,
                                              const float* __restrict__ W,
                                              const float* __restrict__ b,
                                              const float* __restrict__ g,
                                              const float* __restrict__ be,
                                              const float* __restrict__ rm,
                                              const float* __restrict__ rv,
                                              __half* __restrict__ out) {
    __shared__ float Ws[512];
    int tid = threadIdx.x;
    for (int i = tid; i < 512; i += 256) Ws[i] = W[i];
    __syncthreads();
    int wave = (blockIdx.x * 256 + tid) >> 6;
    int lane = tid & 63;
    if (wave >= NN) return;
    int es = lane >> 3, f = lane & 7;
    int st = rowptr[wave], n = cnt[wave];
    float acc = 0.f;
    for (int k0 = 0; k0 < n; k0 += 8) {
        int kk = k0 + es;
        if (kk < n) acc += __half2float(xs[csr[st + kk] * 8 + f]);
    }
    acc += __shfl_xor(acc, 8, 64);
    acc += __shfl_xor(acc, 16, 64);
    acc += __shfl_xor(acc, 32, 64);
    float di = dinv[wave];
    float pf = (acc + __half2float(xs[wave * 8 + f])) * di;
    float scale = g[lane] * rsqrtf(rv[lane] + FEPS);
    float shift = be[lane] + (b[lane] - rm[lane]) * scale;
    float o = 0.f;
#pragma unroll
    for (int k = 0; k < 8; ++k)
        o = fmaf(__shfl(pf, k, 64), Ws[k * 64 + lane], o);
    o = fmaxf(fmaf(o, scale, shift), 0.f);
    out[wave * 64 + lane] = __float2half(o * di);   // pre-scaled for next layer
}

// Layers 2/3: aggregate fp16 Hs (64-wide), transform 64->64, BN, ReLU.
// Index list is shfl-broadcast per 64-edge chunk; loads 8-deep unrolled.
template <bool SCALE_OUT>
__global__ __launch_bounds__(256) void k_gxf64(const __half* __restrict__ Hin,
                                               const int* __restrict__ rowptr,
                                               const int* __restrict__ cnt,
                                               const float* __restrict__ dinv,
                                               const int* __restrict__ csr,
                                               const float* __restrict__ W,
                                               const float* __restrict__ b,
                                               const float* __restrict__ g,
                                               const float* __restrict__ be,
                                               const float* __restrict__ rm,
                                               const float* __restrict__ rv,
                                               __half* __restrict__ out) {
    __shared__ float Ws[4096];
    int tid = threadIdx.x;
    for (int i = tid; i < 4096; i += 256) Ws[i] = W[i];
    __syncthreads();
    int wave = (blockIdx.x * 256 + tid) >> 6;
    int lane = tid & 63;
    if (wave >= NN) return;
    int st = rowptr[wave], n = cnt[wave];
    float a0 = __half2float(Hin[wave * 64 + lane]);  // self (pre-scaled)
    float a1 = 0.f;
    int k = 0;
    while (k < n) {
        int rem = n - k;
        int chunk = rem < 64 ? rem : 64;
        int eidx = (lane < chunk) ? csr[st + k + lane] : 0;
        int j = 0;
        for (; j + 8 <= chunk; j += 8) {
            int s0 = __shfl(eidx, j + 0, 64);
            int s1 = __shfl(eidx, j + 1, 64);
            int s2 = __shfl(eidx, j + 2, 64);
            int s3 = __shfl(eidx, j + 3, 64);
            int s4 = __shfl(eidx, j + 4, 64);
            int s5 = __shfl(eidx, j + 5, 64);
            int s6 = __shfl(eidx, j + 6, 64);
            int s7 = __shfl(eidx, j + 7, 64);
            float v0 = __half2float(Hin[s0 * 64 + lane]);
            float v1 = __half2float(Hin[s1 * 64 + lane]);
            float v2 = __half2float(Hin[s2 * 64 + lane]);
            float v3 = __half2float(Hin[s3 * 64 + lane]);
            float v4 = __half2float(Hin[s4 * 64 + lane]);
            float v5 = __half2float(Hin[s5 * 64 + lane]);
            float v6 = __half2float(Hin[s6 * 64 + lane]);
            float v7 = __half2float(Hin[s7 * 64 + lane]);
            a0 += (v0 + v1) + (v2 + v3);
            a1 += (v4 + v5) + (v6 + v7);
        }
        for (; j < chunk; ++j) {
            int s = __shfl(eidx, j, 64);
            a0 += __half2float(Hin[s * 64 + lane]);
        }
        k += chunk;
    }
    float di = dinv[wave];
    float pf = (a0 + a1) * di;
    float scale = g[lane] * rsqrtf(rv[lane] + FEPS);
    float shift = be[lane] + (b[lane] - rm[lane]) * scale;
    float o0 = 0.f, o1 = 0.f, o2 = 0.f, o3 = 0.f;
#pragma unroll
    for (int k2 = 0; k2 < 64; k2 += 4) {
        o0 = fmaf(__shfl(pf, k2 + 0, 64), Ws[(k2 + 0) * 64 + lane], o0);
        o1 = fmaf(__shfl(pf, k2 + 1, 64), Ws[(k2 + 1) * 64 + lane], o1);
        o2 = fmaf(__shfl(pf, k2 + 2, 64), Ws[(k2 + 2) * 64 + lane], o2);
        o3 = fmaf(__shfl(pf, k2 + 3, 64), Ws[(k2 + 3) * 64 + lane], o3);
    }
    float o = (o0 + o1) + (o2 + o3);
    o = fmaxf(fmaf(o, scale, shift), 0.f);
    if (SCALE_OUT) o *= di;
    out[wave * 64 + lane] = __float2half(o);
}

// ---------- pooling + head ----------

__global__ __launch_bounds__(256) void k_pool(const __half* __restrict__ h,
                                              const int* __restrict__ batch,
                                              float* __restrict__ sums,
                                              float* __restrict__ cnts) {
    const int CHUNK = 32;
    int gw = (blockIdx.x * 256 + threadIdx.x) >> 6;
    int lane = threadIdx.x & 63;
    int nw = (gridDim.x * 256) >> 6;
    int nchunks = (NN + CHUNK - 1) / CHUNK;
    for (int c = gw; c < nchunks; c += nw) {
        int n0 = c * CHUNK;
        int n1 = min(n0 + CHUNK, NN);
        int gcur = batch[n0];
        float accf = 0.f;
        float cntf = 0.f;
        for (int n = n0; n < n1; ++n) {
            int gg = batch[n];
            if (gg != gcur) {
                atomicAdd(&sums[gcur * 64 + lane], accf);
                if (lane == 0) atomicAdd(&cnts[gcur], cntf);
                accf = 0.f;
                cntf = 0.f;
                gcur = gg;
            }
            accf += __half2float(h[n * 64 + lane]);
            cntf += 1.f;
        }
        atomicAdd(&sums[gcur * 64 + lane], accf);
        if (lane == 0) atomicAdd(&cnts[gcur], cntf);
    }
}

__global__ __launch_bounds__(256) void k_head(const float* __restrict__ sums,
                                              const float* __restrict__ cnts,
                                              const float* __restrict__ Wr1,
                                              const float* __restrict__ br1,
                                              const float* __restrict__ Wr2,
                                              const float* __restrict__ br2,
                                              float* __restrict__ out) {
    int wave = (blockIdx.x * 256 + threadIdx.x) >> 6;
    int lane = threadIdx.x & 63;
    if (wave >= NG) return;
    float c = fmaxf(cnts[wave], 1.0f);
    float pooled = sums[wave * 64 + lane] / c;
    float acc = 0.f;
#pragma unroll
    for (int k = 0; k < 64; ++k)
        acc = fmaf(__shfl(pooled, k, 64), Wr1[k * 64 + lane], acc);
    float hid = fmaxf(acc + br1[lane], 0.f);
    float o0 = hid * Wr2[lane * 2 + 0];
    float o1 = hid * Wr2[lane * 2 + 1];
#pragma unroll
    for (int off = 32; off > 0; off >>= 1) {
        o0 += __shfl_xor(o0, off, 64);
        o1 += __shfl_xor(o1, off, 64);
    }
    if (lane == 0) {
        out[wave * 2 + 0] = o0 + br2[0];
        out[wave * 2 + 1] = o1 + br2[1];
    }
}

extern "C" void kernel_launch(void* const* d_in, const int* in_sizes, int n_in,
                              void* d_out, int out_size, void* d_ws, size_t ws_size,
                              hipStream_t stream) {
    const float* x   = (const float*)d_in[0];
    const int*   ei  = (const int*)d_in[1];     // [2, E]: row0=src, row1=dst
    const int*   bat = (const int*)d_in[2];
    const float* W1  = (const float*)d_in[3];
    const float* b1  = (const float*)d_in[4];
    const float* g1  = (const float*)d_in[5];
    const float* be1 = (const float*)d_in[6];
    const float* rm1 = (const float*)d_in[7];
    const float* rv1 = (const float*)d_in[8];
    const float* W2  = (const float*)d_in[9];
    const float* b2  = (const float*)d_in[10];
    const float* g2  = (const float*)d_in[11];
    const float* be2 = (const float*)d_in[12];
    const float* rm2 = (const float*)d_in[13];
    const float* rv2 = (const float*)d_in[14];
    const float* W3  = (const float*)d_in[15];
    const float* b3  = (const float*)d_in[16];
    const float* g3  = (const float*)d_in[17];
    const float* be3 = (const float*)d_in[18];
    const float* rm3 = (const float*)d_in[19];
    const float* rv3 = (const float*)d_in[20];
    const float* Wr1 = (const float*)d_in[21];
    const float* br1 = (const float*)d_in[22];
    const float* Wr2 = (const float*)d_in[23];
    const float* br2 = (const float*)d_in[24];
    float* out = (float*)d_out;

    // workspace layout (4-byte words)
    int*    cnt    = (int*)d_ws;               // NN
    int*    rowptr = cnt + NN;                 // NN
    int*    bsum   = rowptr + NN;              // 512
    int*    bh     = bsum + 512;               // NB
    int*    bboff  = bh + NB;                  // NB+1
    int*    bcur   = bboff + NB + 1;           // NB
    float*  dinv   = (float*)(bcur + NB);      // NN
    int*    csr    = (int*)(dinv + NN);        // NE
    __half* xs     = (__half*)(csr + NE);      // NN*8 halves (NN*4 words)
    float*  sums   = (float*)(xs + NN * 8);    // NG*64
    float*  cnts   = sums + NG * 64;           // NG
    __half* A      = (__half*)(cnts + NG);     // NF halves (NF/2 words)
    __half* B      = A + NF;                   // NF halves
    int2*   ebuf   = (int2*)A;                 // NE int2 (= 2*NE words), aliases A+B
                                               // (dead before layer 1 writes A)

    const int* srcI = ei;
    const int* dstI = ei + NE;

    const int gA = ceil_div(NE, CHA);        // 391
    const int gN = ceil_div(NN, 256);        // 391
    const int gW = ceil_div(NN * 64, 256);   // wave-per-node kernels

    hipMemsetAsync(bh, 0, NB * sizeof(int), stream);
    hipMemsetAsync(sums, 0, (NG * 64 + NG) * sizeof(float), stream);

    // pass A: bucket partition
    kA_hist<<<gA, 256, 0, stream>>>(dstI, bh);
    kA_scan<<<1, 512, 0, stream>>>(bh, bboff, bcur);
    kA_fill<<<gA, 256, 0, stream>>>(srcI, dstI, bcur, ebuf);

    // pass B: node counts, scan, CSR fill
    kB_hist<<<NB, 256, 0, stream>>>(ebuf, bboff, cnt);
    k_dinv_xs<<<gN, 256, 0, stream>>>(cnt, x, dinv, xs);
    k_scan1<<<gN, 256, 0, stream>>>(cnt, bsum);
    k_scan2<<<1, 512, 0, stream>>>(bsum, gN);
    k_scan3<<<gN, 256, 0, stream>>>(cnt, bsum, rowptr);
    kB_fill<<<NB, 256, 0, stream>>>(ebuf, bboff, rowptr, csr);

    // layers (fused gather + transform + BN + ReLU), fp16 feature storage
    k_gxf8<<<gW, 256, 0, stream>>>(xs, rowptr, cnt, dinv, csr,
                                   W1, b1, g1, be1, rm1, rv1, A);
    k_gxf64<true><<<gW, 256, 0, stream>>>(A, rowptr, cnt, dinv, csr,
                                          W2, b2, g2, be2, rm2, rv2, B);
    k_gxf64<false><<<gW, 256, 0, stream>>>(B, rowptr, cnt, dinv, csr,
                                           W3, b3, g3, be3, rm3, rv3, A);

    // mean pool + head
    k_pool<<<800, 256, 0, stream>>>(A, bat, sums, cnts);
    k_head<<<ceil_div(NG * 64, 256), 256, 0, stream>>>(sums, cnts, Wr1, br1, Wr2, br2, out);
}

// Round 6
// 619.807 us; speedup vs baseline: 4.1084x; 1.0464x over previous
//
#include <hip/hip_runtime.h>
#include <hip/hip_fp16.h>

#define NN 100000
#define NE 3200000
#define NG 256
#define NF (NN * 64)
#define FEPS 1e-5f
#define BSH 8                       // 256 dst-nodes per bucket
#define NB ((NN + 255) >> 8)        // 391 buckets
#define CHA 8192                    // edges per block in pass A

static inline int ceil_div(int a, int b) { return (a + b - 1) / b; }

// ---------- pass A: coarse bucket partition of edges ----------

__global__ __launch_bounds__(256) void kA_hist(const int* __restrict__ dst,
                                               int* __restrict__ bh) {
    __shared__ int lh[NB];
    int t = threadIdx.x;
    for (int b = t; b < NB; b += 256) lh[b] = 0;
    __syncthreads();
    int e0 = blockIdx.x * CHA;
    int e1 = min(e0 + CHA, NE);
    for (int i = e0 + t; i < e1; i += 256) atomicAdd(&lh[dst[i] >> BSH], 1);
    __syncthreads();
    for (int b = t; b < NB; b += 256)
        if (lh[b]) atomicAdd(&bh[b], lh[b]);
}

__global__ __launch_bounds__(512) void kA_scan(const int* __restrict__ bh,
                                               int* __restrict__ bboff,
                                               int* __restrict__ bcur) {
    __shared__ int s[512];
    int t = threadIdx.x;
    int v = (t < NB) ? bh[t] : 0;
    s[t] = v;
    __syncthreads();
    for (int off = 1; off < 512; off <<= 1) {
        int add = (t >= off) ? s[t - off] : 0;
        __syncthreads();
        s[t] += add;
        __syncthreads();
    }
    if (t < NB) {
        int ex = s[t] - v;
        bboff[t] = ex;
        bcur[t] = ex;
    }
    if (t == 0) bboff[NB] = NE;
}

__global__ __launch_bounds__(256) void kA_fill(const int* __restrict__ src,
                                               const int* __restrict__ dst,
                                               int* __restrict__ bcur,
                                               int2* __restrict__ ebuf) {
    __shared__ int lh[NB];
    __shared__ int lbase[NB];
    __shared__ int lcur[NB];
    int t = threadIdx.x;
    for (int b = t; b < NB; b += 256) lh[b] = 0;
    __syncthreads();
    int e0 = blockIdx.x * CHA;
    int e1 = min(e0 + CHA, NE);
    for (int i = e0 + t; i < e1; i += 256) atomicAdd(&lh[dst[i] >> BSH], 1);
    __syncthreads();
    for (int b = t; b < NB; b += 256) {
        int c = lh[b];
        lbase[b] = c ? atomicAdd(&bcur[b], c) : 0;
        lcur[b] = 0;
    }
    __syncthreads();
    for (int i = e0 + t; i < e1; i += 256) {
        int d = dst[i];
        int s = src[i];
        int b = d >> BSH;
        int p = atomicAdd(&lcur[b], 1);
        ebuf[lbase[b] + p] = make_int2(s, d);
    }
}

// ---------- pass B: per-bucket node hist + CSR fill ----------

__global__ __launch_bounds__(256) void kB_hist(const int2* __restrict__ ebuf,
                                               const int* __restrict__ bboff,
                                               int* __restrict__ cnt) {
    __shared__ int lc[256];
    int b = blockIdx.x;
    int t = threadIdx.x;
    lc[t] = 0;
    __syncthreads();
    int st = bboff[b], en = bboff[b + 1];
    for (int i = st + t; i < en; i += 256) atomicAdd(&lc[ebuf[i].y & 255], 1);
    __syncthreads();
    int node = (b << BSH) + t;
    if (node < NN) cnt[node] = lc[t];
}

// dinv[i] = rsqrt(in_deg + 1); xs[i,:] = fp16(x[i,:] * dinv[i])
__global__ __launch_bounds__(256) void k_dinv_xs(const int* __restrict__ cnt,
                                                 const float* __restrict__ x,
                                                 float* __restrict__ dinv,
                                                 __half* __restrict__ xs) {
    int i = blockIdx.x * 256 + threadIdx.x;
    if (i >= NN) return;
    float di = rsqrtf((float)cnt[i] + 1.0f);
    dinv[i] = di;
#pragma unroll
    for (int f = 0; f < 8; ++f) xs[i * 8 + f] = __float2half(x[i * 8 + f] * di);
}

__global__ __launch_bounds__(256) void k_scan1(const int* __restrict__ cnt,
                                               int* __restrict__ bsum) {
    __shared__ int s[256];
    int t = threadIdx.x;
    int i = blockIdx.x * 256 + t;
    s[t] = (i < NN) ? cnt[i] : 0;
    __syncthreads();
    for (int off = 128; off > 0; off >>= 1) {
        if (t < off) s[t] += s[t + off];
        __syncthreads();
    }
    if (t == 0) bsum[blockIdx.x] = s[0];
}

__global__ __launch_bounds__(512) void k_scan2(int* __restrict__ bsum, int nb) {
    __shared__ int s[512];
    int t = threadIdx.x;
    int v = (t < nb) ? bsum[t] : 0;
    s[t] = v;
    __syncthreads();
    for (int off = 1; off < 512; off <<= 1) {
        int add = (t >= off) ? s[t - off] : 0;
        __syncthreads();
        s[t] += add;
        __syncthreads();
    }
    if (t < nb) bsum[t] = s[t] - v;   // exclusive
}

__global__ __launch_bounds__(256) void k_scan3(const int* __restrict__ cnt,
                                               const int* __restrict__ bsum,
                                               int* __restrict__ rowptr) {
    __shared__ int s[256];
    int t = threadIdx.x;
    int i = blockIdx.x * 256 + t;
    int v = (i < NN) ? cnt[i] : 0;
    s[t] = v;
    __syncthreads();
    for (int off = 1; off < 256; off <<= 1) {
        int add = (t >= off) ? s[t - off] : 0;
        __syncthreads();
        s[t] += add;
        __syncthreads();
    }
    if (i < NN) rowptr[i] = s[t] - v + bsum[blockIdx.x];
}

__global__ __launch_bounds__(256) void kB_fill(const int2* __restrict__ ebuf,
                                               const int* __restrict__ bboff,
                                               const int* __restrict__ rowptr,
                                               int* __restrict__ csr) {
    __shared__ int rp[256];
    __shared__ int lc[256];
    int b = blockIdx.x;
    int t = threadIdx.x;
    int node = (b << BSH) + t;
    rp[t] = (node < NN) ? rowptr[node] : 0;
    lc[t] = 0;
    __syncthreads();
    int st = bboff[b], en = bboff[b + 1];
    for (int i = st + t; i < en; i += 256) {
        int2 e = ebuf[i];
        int dl = e.y & 255;
        int p = atomicAdd(&lc[dl], 1);
        csr[rp[dl] + p] = e.x;
    }
}

// nodes-per-graph via run-length over sorted batch (64-node chunks/thread)
__global__ __launch_bounds__(256) void k_cnts(const int* __restrict__ batch,
                                              float* __restrict__ cnts) {
    int c = blockIdx.x * 256 + threadIdx.x;
    int n0 = c * 64;
    if (n0 >= NN) return;
    int n1 = min(n0 + 64, NN);
    int gcur = batch[n0];
    float cf = 0.f;
    for (int n = n0; n < n1; ++n) {
        int gg = batch[n];
        if (gg != gcur) {
            atomicAdd(&cnts[gcur], cf);
            cf = 0.f;
            gcur = gg;
        }
        cf += 1.f;
    }
    atomicAdd(&cnts[gcur], cf);
}

// ---------- fused gather + transform + BN + ReLU ----------

// Layer 1: aggregate xs (half2 pairs, 16 edges/iter), 8->64, BN, ReLU, x dinv.
__global__ __launch_bounds__(256) void k_gxf8(const __half2* __restrict__ xs2,
                                              const int* __restrict__ rowptr,
                                              const int* __restrict__ cnt,
                                              const float* __restrict__ dinv,
                                              const int* __restrict__ csr,
                                              const float* __restrict__ W,
                                              const float* __restrict__ b,
                                              const float* __restrict__ g,
                                              const float* __restrict__ be,
                                              const float* __restrict__ rm,
                                              const float* __restrict__ rv,
                                              __half* __restrict__ out) {
    __shared__ float Ws[512];
    int tid = threadIdx.x;
    for (int i = tid; i < 512; i += 256) Ws[i] = W[i];
    __syncthreads();
    int wave = (blockIdx.x * 256 + tid) >> 6;
    int lane = tid & 63;
    if (wave >= NN) return;
    int es = lane >> 2, q = lane & 3;     // es: 16 edges/iter, q: feature pair
    int st = rowptr[wave], n = cnt[wave];
    float ax = 0.f, ay = 0.f;
    for (int k0 = 0; k0 < n; k0 += 16) {
        int kk = k0 + es;
        if (kk < n) {
            float2 f = __half22float2(xs2[csr[st + kk] * 4 + q]);
            ax += f.x; ay += f.y;
        }
    }
    // reduce over es (lane bits 2..5)
    ax += __shfl_xor(ax, 4, 64);  ay += __shfl_xor(ay, 4, 64);
    ax += __shfl_xor(ax, 8, 64);  ay += __shfl_xor(ay, 8, 64);
    ax += __shfl_xor(ax, 16, 64); ay += __shfl_xor(ay, 16, 64);
    ax += __shfl_xor(ax, 32, 64); ay += __shfl_xor(ay, 32, 64);
    float di = dinv[wave];
    float2 s2 = __half22float2(xs2[wave * 4 + q]);
    float pfx = (ax + s2.x) * di;
    float pfy = (ay + s2.y) * di;
    float scale = g[lane] * rsqrtf(rv[lane] + FEPS);
    float shift = be[lane] + (b[lane] - rm[lane]) * scale;
    float o = 0.f;
#pragma unroll
    for (int qq = 0; qq < 4; ++qq) {
        float vx = __shfl(pfx, qq, 64);   // lane qq holds pair qq
        float vy = __shfl(pfy, qq, 64);
        o = fmaf(vx, Ws[(2 * qq) * 64 + lane], o);
        o = fmaf(vy, Ws[(2 * qq + 1) * 64 + lane], o);
    }
    o = fmaxf(fmaf(o, scale, shift), 0.f);
    out[wave * 64 + lane] = __float2half(o * di);   // pre-scaled for next layer
}

// Layers 2/3: half2-paired gather (2 edges per wave-load), 64->64, BN, ReLU.
// POOL=false: write half(o*dinv). POOL=true: atomic mean-pool accumulate.
template <bool POOL>
__global__ __launch_bounds__(256) void k_gxf64(const __half2* __restrict__ Hin2,
                                               const int* __restrict__ rowptr,
                                               const int* __restrict__ cnt,
                                               const float* __restrict__ dinv,
                                               const int* __restrict__ csr,
                                               const float* __restrict__ W,
                                               const float* __restrict__ b,
                                               const float* __restrict__ g,
                                               const float* __restrict__ be,
                                               const float* __restrict__ rm,
                                               const float* __restrict__ rv,
                                               const int* __restrict__ batch,
                                               __half* __restrict__ out,
                                               float* __restrict__ sums) {
    __shared__ float Ws[4096];
    int tid = threadIdx.x;
    for (int i = tid; i < 4096; i += 256) Ws[i] = W[i];
    __syncthreads();
    int wave = (blockIdx.x * 256 + tid) >> 6;
    int lane = tid & 63;
    if (wave >= NN) return;
    int p = lane >> 5;                    // which edge of pair
    int q = lane & 31;                    // feature-pair index
    int st = rowptr[wave], n = cnt[wave];
    float ax = 0.f, ay = 0.f;
    int k = 0;
    while (k < n) {
        int rem = n - k;
        int chunk = rem < 64 ? rem : 64;
        int eidx = (lane < chunk) ? csr[st + k + lane] : 0;
        int j = 0;
        for (; j + 16 <= chunk; j += 16) {   // 8 pairs = 16 edges
            int s0 = __shfl(eidx, j + 0 + p, 64);
            int s1 = __shfl(eidx, j + 2 + p, 64);
            int s2 = __shfl(eidx, j + 4 + p, 64);
            int s3 = __shfl(eidx, j + 6 + p, 64);
            int s4 = __shfl(eidx, j + 8 + p, 64);
            int s5 = __shfl(eidx, j + 10 + p, 64);
            int s6 = __shfl(eidx, j + 12 + p, 64);
            int s7 = __shfl(eidx, j + 14 + p, 64);
            float2 f0 = __half22float2(Hin2[s0 * 32 + q]);
            float2 f1 = __half22float2(Hin2[s1 * 32 + q]);
            float2 f2 = __half22float2(Hin2[s2 * 32 + q]);
            float2 f3 = __half22float2(Hin2[s3 * 32 + q]);
            float2 f4 = __half22float2(Hin2[s4 * 32 + q]);
            float2 f5 = __half22float2(Hin2[s5 * 32 + q]);
            float2 f6 = __half22float2(Hin2[s6 * 32 + q]);
            float2 f7 = __half22float2(Hin2[s7 * 32 + q]);
            ax += ((f0.x + f1.x) + (f2.x + f3.x)) + ((f4.x + f5.x) + (f6.x + f7.x));
            ay += ((f0.y + f1.y) + (f2.y + f3.y)) + ((f4.y + f5.y) + (f6.y + f7.y));
        }
        for (; j + 2 <= chunk; j += 2) {
            int s = __shfl(eidx, j + p, 64);
            float2 f = __half22float2(Hin2[s * 32 + q]);
            ax += f.x; ay += f.y;
        }
        if (j < chunk) {                 // odd leftover: p==0 half only
            int s = __shfl(eidx, j, 64);
            if (p == 0) {
                float2 f = __half22float2(Hin2[s * 32 + q]);
                ax += f.x; ay += f.y;
            }
        }
        k += chunk;
    }
    // combine the two edge-halves
    ax += __shfl_xor(ax, 32, 64);
    ay += __shfl_xor(ay, 32, 64);
    float di = dinv[wave];
    float2 s2 = __half22float2(Hin2[wave * 32 + q]);   // self (pre-scaled)
    float pfx = (ax + s2.x) * di;
    float pfy = (ay + s2.y) * di;
    float scale = g[lane] * rsqrtf(rv[lane] + FEPS);
    float shift = be[lane] + (b[lane] - rm[lane]) * scale;
    float o0 = 0.f, o1 = 0.f;
#pragma unroll
    for (int qq = 0; qq < 32; ++qq) {
        float vx = __shfl(pfx, qq, 64);   // lane qq (p=0,q=qq) holds pair qq
        float vy = __shfl(pfy, qq, 64);
        o0 = fmaf(vx, Ws[(2 * qq) * 64 + lane], o0);
        o1 = fmaf(vy, Ws[(2 * qq + 1) * 64 + lane], o1);
    }
    float o = o0 + o1;
    o = fmaxf(fmaf(o, scale, shift), 0.f);
    if (POOL) {
        int gg = batch[wave];
        atomicAdd(&sums[gg * 64 + lane], o);
    } else {
        out[wave * 64 + lane] = __float2half(o * di);
    }
}

// ---------- head ----------

__global__ __launch_bounds__(256) void k_head(const float* __restrict__ sums,
                                              const float* __restrict__ cnts,
                                              const float* __restrict__ Wr1,
                                              const float* __restrict__ br1,
                                              const float* __restrict__ Wr2,
                                              const float* __restrict__ br2,
                                              float* __restrict__ out) {
    int wave = (blockIdx.x * 256 + threadIdx.x) >> 6;
    int lane = threadIdx.x & 63;
    if (wave >= NG) return;
    float c = fmaxf(cnts[wave], 1.0f);
    float pooled = sums[wave * 64 + lane] / c;
    float acc = 0.f;
#pragma unroll
    for (int k = 0; k < 64; ++k)
        acc = fmaf(__shfl(pooled, k, 64), Wr1[k * 64 + lane], acc);
    float hid = fmaxf(acc + br1[lane], 0.f);
    float o0 = hid * Wr2[lane * 2 + 0];
    float o1 = hid * Wr2[lane * 2 + 1];
#pragma unroll
    for (int off = 32; off > 0; off >>= 1) {
        o0 += __shfl_xor(o0, off, 64);
        o1 += __shfl_xor(o1, off, 64);
    }
    if (lane == 0) {
        out[wave * 2 + 0] = o0 + br2[0];
        out[wave * 2 + 1] = o1 + br2[1];
    }
}

extern "C" void kernel_launch(void* const* d_in, const int* in_sizes, int n_in,
                              void* d_out, int out_size, void* d_ws, size_t ws_size,
                              hipStream_t stream) {
    const float* x   = (const float*)d_in[0];
    const int*   ei  = (const int*)d_in[1];     // [2, E]: row0=src, row1=dst
    const int*   bat = (const int*)d_in[2];
    const float* W1  = (const float*)d_in[3];
    const float* b1  = (const float*)d_in[4];
    const float* g1  = (const float*)d_in[5];
    const float* be1 = (const float*)d_in[6];
    const float* rm1 = (const float*)d_in[7];
    const float* rv1 = (const float*)d_in[8];
    const float* W2  = (const float*)d_in[9];
    const float* b2  = (const float*)d_in[10];
    const float* g2  = (const float*)d_in[11];
    const float* be2 = (const float*)d_in[12];
    const float* rm2 = (const float*)d_in[13];
    const float* rv2 = (const float*)d_in[14];
    const float* W3  = (const float*)d_in[15];
    const float* b3  = (const float*)d_in[16];
    const float* g3  = (const float*)d_in[17];
    const float* be3 = (const float*)d_in[18];
    const float* rm3 = (const float*)d_in[19];
    const float* rv3 = (const float*)d_in[20];
    const float* Wr1 = (const float*)d_in[21];
    const float* br1 = (const float*)d_in[22];
    const float* Wr2 = (const float*)d_in[23];
    const float* br2 = (const float*)d_in[24];
    float* out = (float*)d_out;

    // workspace layout (4-byte words)
    int*    cnt    = (int*)d_ws;               // NN
    int*    rowptr = cnt + NN;                 // NN
    int*    bsum   = rowptr + NN;              // 512
    int*    bh     = bsum + 512;               // NB
    int*    bboff  = bh + NB;                  // NB+1
    int*    bcur   = bboff + NB + 1;           // NB
    float*  dinv   = (float*)(bcur + NB);      // NN
    int*    csr    = (int*)(dinv + NN);        // NE
    __half* xs     = (__half*)(csr + NE);      // NN*8 halves
    float*  sums   = (float*)(xs + NN * 8);    // NG*64
    float*  cnts   = sums + NG * 64;           // NG
    __half* A      = (__half*)(cnts + NG);     // NF halves
    __half* B      = A + NF;                   // NF halves
    int2*   ebuf   = (int2*)A;                 // NE int2, aliases A+B (dead
                                               //  before layer 1 writes A)

    const int* srcI = ei;
    const int* dstI = ei + NE;

    const int gA = ceil_div(NE, CHA);        // 391
    const int gN = ceil_div(NN, 256);        // 391
    const int gW = ceil_div(NN * 64, 256);   // wave-per-node kernels

    hipMemsetAsync(bh, 0, NB * sizeof(int), stream);
    hipMemsetAsync(sums, 0, (NG * 64 + NG) * sizeof(float), stream);

    // pass A: bucket partition
    kA_hist<<<gA, 256, 0, stream>>>(dstI, bh);
    kA_scan<<<1, 512, 0, stream>>>(bh, bboff, bcur);
    kA_fill<<<gA, 256, 0, stream>>>(srcI, dstI, bcur, ebuf);

    // pass B: node counts, scan, CSR fill (+ graph-size counts)
    kB_hist<<<NB, 256, 0, stream>>>(ebuf, bboff, cnt);
    k_dinv_xs<<<gN, 256, 0, stream>>>(cnt, x, dinv, xs);
    k_cnts<<<ceil_div(ceil_div(NN, 64), 256), 256, 0, stream>>>(bat, cnts);
    k_scan1<<<gN, 256, 0, stream>>>(cnt, bsum);
    k_scan2<<<1, 512, 0, stream>>>(bsum, gN);
    k_scan3<<<gN, 256, 0, stream>>>(cnt, bsum, rowptr);
    kB_fill<<<NB, 256, 0, stream>>>(ebuf, bboff, rowptr, csr);

    // layers (fused gather + transform + BN + ReLU), fp16 feature storage
    k_gxf8<<<gW, 256, 0, stream>>>((const __half2*)xs, rowptr, cnt, dinv, csr,
                                   W1, b1, g1, be1, rm1, rv1, A);
    k_gxf64<false><<<gW, 256, 0, stream>>>((const __half2*)A, rowptr, cnt, dinv, csr,
                                           W2, b2, g2, be2, rm2, rv2,
                                           bat, B, nullptr);
    // layer 3 fused with mean-pool accumulation (no H write)
    k_gxf64<true><<<gW, 256, 0, stream>>>((const __half2*)B, rowptr, cnt, dinv, csr,
                                          W3, b3, g3, be3, rm3, rv3,
                                          bat, nullptr, sums);

    k_head<<<ceil_div(NG * 64, 256), 256, 0, stream>>>(sums, cnts, Wr1, br1, Wr2, br2, out);
}